// Round 1
// baseline (147.941 us; speedup 1.0000x reference)
//
#include <hip/hip_runtime.h>

// Problem constants (from reference): B=4, M=8, N=128, D=32, H=64, hidden=2D=64
#define BN 4
#define MN 8
#define NN 128
#define DD 32
#define KK 64          // 2*D == H == 64
constexpr int ND = NN * DD;   // 4096 elements per (b,m) slice
constexpr int NK = NN * KK;   // 8192

__device__ __forceinline__ float gelu_t(float v) {
    // JAX approximate gelu: 0.5*x*(1+tanh(sqrt(2/pi)*(x+0.044715 x^3)))
    float u  = 0.7978845608028654f * (v + 0.044715f * v * v * v);
    float e  = __expf(2.0f * u);
    float th = 1.0f - 2.0f / (e + 1.0f);
    return 0.5f * v * (1.0f + th);
}

// ---------------------------------------------------------------------------
// Kernel 1: one block per (b,m). Set-norm, MLP1, A1 = x1@W2a + b2a,
// A2 = xn@W2a, all staged through LDS. Block 0 also computes v2 = W2b@w3
// and c3 = b2b.w3.
// ---------------------------------------------------------------------------
__global__ __launch_bounds__(512) void prep_kernel(
    const float* __restrict__ x, const float* __restrict__ x_size,
    const float* __restrict__ W1a, const float* __restrict__ b1a,
    const float* __restrict__ W1b, const float* __restrict__ b1b,
    const float* __restrict__ W2a, const float* __restrict__ b2a,
    const float* __restrict__ W2b, const float* __restrict__ b2b,
    const float* __restrict__ w3,
    float* __restrict__ x1g, float* __restrict__ A1g, float* __restrict__ A2g,
    float* __restrict__ v2g, float* __restrict__ c3g)
{
    __shared__ float sX[ND];
    __shared__ float sXn[ND];
    __shared__ float sH[NK];
    __shared__ float sX1[ND];
    __shared__ float sW1a[DD * KK];
    __shared__ float sW1b[KK * DD];
    __shared__ float sW2a[DD * KK];
    __shared__ float sB1a[KK];
    __shared__ float sB2a[KK];
    __shared__ float sB1b[DD];
    __shared__ float sMask[NN];
    __shared__ float sM1[NN];
    __shared__ float sRed[8];

    const int tid = threadIdx.x;
    const int bm  = blockIdx.x;
    const int b   = bm / MN;
    const float* xp = x + (size_t)bm * ND;

    // Stage weights into LDS
    for (int i = tid; i < DD * KK; i += 512) {
        sW1a[i] = W1a[i];
        sW1b[i] = W1b[i];
        sW2a[i] = W2a[i];
    }
    if (tid < KK) { sB1a[tid] = b1a[tid]; sB2a[tid] = b2a[tid]; }
    if (tid < DD) { sB1b[tid] = b1b[tid]; }

    // ---- load x slice + total sum ----
    float lsum = 0.f;
    for (int i = tid; i < ND; i += 512) {
        float v = xp[i];
        sX[i] = v;
        lsum += v;
    }
    #pragma unroll
    for (int off = 32; off; off >>= 1) lsum += __shfl_xor(lsum, off);
    __syncthreads();
    if ((tid & 63) == 0) sRed[tid >> 6] = lsum;
    __syncthreads();
    float total = 0.f;
    #pragma unroll
    for (int w = 0; w < 8; ++w) total += sRed[w];
    const float denom = x_size[b] * (float)DD;
    const float mean  = total / denom;

    // row mask from x (any nonzero in row)
    if (tid < NN) {
        const float* r = &sX[tid * DD];
        float any = 0.f;
        #pragma unroll
        for (int d = 0; d < DD; ++d) if (r[d] != 0.f) any = 1.f;
        sMask[tid] = any;
    }
    __syncthreads();

    // ---- masked squared-diff sum -> std ----
    float lsq = 0.f;
    for (int i = tid; i < ND; i += 512) {
        int n = i >> 5;
        float v = sX[i] - mean;
        lsq += (sMask[n] != 0.f) ? v * v : 0.f;
    }
    #pragma unroll
    for (int off = 32; off; off >>= 1) lsq += __shfl_xor(lsq, off);
    __syncthreads();
    if ((tid & 63) == 0) sRed[tid >> 6] = lsq;
    __syncthreads();
    float sq = 0.f;
    #pragma unroll
    for (int w = 0; w < 8; ++w) sq += sRed[w];
    const float stdv = sqrtf(sq / denom);
    const float inv  = 1.0f / (stdv + 1e-8f);

    for (int i = tid; i < ND; i += 512) {
        int n = i >> 5;
        sXn[i] = (sMask[n] != 0.f) ? (sX[i] - mean) * inv : 0.f;
    }
    __syncthreads();

    // m1 = item_mask(xn)
    if (tid < NN) {
        const float* r = &sXn[tid * DD];
        float any = 0.f;
        #pragma unroll
        for (int d = 0; d < DD; ++d) if (r[d] != 0.f) any = 1.f;
        sM1[tid] = any;
    }
    __syncthreads();

    // ---- H = gelu(xn @ W1a + b1a)  [N x K] ----
    for (int i = tid; i < NK; i += 512) {
        int n = i >> 6, k = i & 63;
        const float* r = &sXn[n * DD];
        float acc = sB1a[k];
        #pragma unroll
        for (int d = 0; d < DD; ++d) acc += r[d] * sW1a[d * KK + k];
        sH[i] = gelu_t(acc);
    }
    __syncthreads();

    // ---- x1 = (H @ W1b + b1b) * m1  [N x D] ----
    for (int i = tid; i < ND; i += 512) {
        int n = i >> 5, d = i & 31;
        const float* hr = &sH[n * KK];
        float acc = sB1b[d];
        #pragma unroll
        for (int k = 0; k < KK; ++k) acc += hr[k] * sW1b[k * DD + d];
        float v = acc * sM1[n];
        sX1[i] = v;
        x1g[(size_t)bm * ND + i] = v;
    }
    __syncthreads();

    // ---- A1 = x1 @ W2a + b2a ; A2 = xn @ W2a  [N x K] ----
    for (int i = tid; i < NK; i += 512) {
        int n = i >> 6, k = i & 63;
        const float* r1 = &sX1[n * DD];
        const float* r2 = &sXn[n * DD];
        float a1 = sB2a[k], a2 = 0.f;
        #pragma unroll
        for (int d = 0; d < DD; ++d) {
            a1 += r1[d] * sW2a[d * KK + k];
            a2 += r2[d] * sW2a[d * KK + k];
        }
        A1g[(size_t)bm * NK + i] = a1;
        A2g[(size_t)bm * NK + i] = a2;
    }

    // ---- v2 = W2b @ w3, c3 = b2b . w3 (block 0 only) ----
    if (bm == 0) {
        if (tid < KK) {
            float acc = 0.f;
            for (int h = 0; h < KK; ++h) acc += W2b[tid * KK + h] * w3[h];
            v2g[tid] = acc;
        }
        if (tid == 0) {
            float acc = 0.f;
            for (int h = 0; h < KK; ++h) acc += b2b[h] * w3[h];
            c3g[0] = acc;
        }
    }
}

// ---------------------------------------------------------------------------
// Kernel 2: one block per output row (b,m,j). 4 waves; lane k holds A2[j,k]
// and v2[k]; loop i: S[i,j] = sum_k gelu(A1[i,k]-A2[j,k])*v2[k] + c3 via
// butterfly reduce, then acc[d] += S * x1[i,d].
// ---------------------------------------------------------------------------
__global__ __launch_bounds__(256) void pair_kernel(
    const float* __restrict__ x, const float* __restrict__ b3,
    const float* __restrict__ x1g, const float* __restrict__ A1g,
    const float* __restrict__ A2g, const float* __restrict__ v2g,
    const float* __restrict__ c3g, float* __restrict__ out)
{
    __shared__ float sAcc[4][DD];
    const int jg   = blockIdx.x;        // 0 .. B*M*N-1
    const int bm   = jg >> 7;
    const int tid  = threadIdx.x;
    const int wave = tid >> 6;
    const int lane = tid & 63;

    const float a2 = A2g[(size_t)jg * KK + lane];
    const float v2 = v2g[lane];
    const float c3 = c3g[0];

    const float* A1bm = A1g + (size_t)bm * NK;
    const float* x1bm = x1g + (size_t)bm * ND;

    float acc = 0.f;
    for (int i = wave; i < NN; i += 4) {
        float a1 = A1bm[i * KK + lane];
        float t  = gelu_t(a1 - a2) * v2;
        #pragma unroll
        for (int off = 32; off; off >>= 1) t += __shfl_xor(t, off);
        float S   = t + c3;
        float x1v = (lane < DD) ? x1bm[i * DD + lane] : 0.f;
        acc += S * x1v;
    }
    if (lane < DD) sAcc[wave][lane] = acc;
    __syncthreads();

    if (wave == 0) {
        float xv = 0.f;
        if (lane < DD) xv = x[(size_t)jg * DD + lane];
        unsigned long long nb = __ballot(xv != 0.f);
        float maskf = (nb != 0ull) ? 1.f : 0.f;
        if (lane < DD) {
            float total = sAcc[0][lane] + sAcc[1][lane] + sAcc[2][lane] + sAcc[3][lane];
            out[(size_t)jg * DD + lane] = (total + b3[0] + xv) * maskf;
        }
    }
}

extern "C" void kernel_launch(void* const* d_in, const int* in_sizes, int n_in,
                              void* d_out, int out_size, void* d_ws, size_t ws_size,
                              hipStream_t stream) {
    const float* x      = (const float*)d_in[0];
    const float* x_size = (const float*)d_in[1];
    const float* W1a    = (const float*)d_in[2];
    const float* b1a    = (const float*)d_in[3];
    const float* W1b    = (const float*)d_in[4];
    const float* b1b    = (const float*)d_in[5];
    const float* W2a    = (const float*)d_in[6];
    const float* b2a    = (const float*)d_in[7];
    const float* W2b    = (const float*)d_in[8];
    const float* b2b    = (const float*)d_in[9];
    const float* w3     = (const float*)d_in[10];
    const float* b3     = (const float*)d_in[11];
    float* out = (float*)d_out;

    // Workspace layout (floats): x1 | A1 | A2 | v2 | c3  (~2.6 MB total)
    float* ws  = (float*)d_ws;
    float* x1g = ws;                               // B*M*N*D  = 131072
    float* A1g = x1g + (size_t)BN * MN * NN * DD;  // B*M*N*K  = 262144
    float* A2g = A1g + (size_t)BN * MN * NN * KK;  // B*M*N*K  = 262144
    float* v2g = A2g + (size_t)BN * MN * NN * KK;  // 64
    float* c3g = v2g + KK;                         // 1

    prep_kernel<<<BN * MN, 512, 0, stream>>>(
        x, x_size, W1a, b1a, W1b, b1b, W2a, b2a, W2b, b2b, w3,
        x1g, A1g, A2g, v2g, c3g);

    pair_kernel<<<BN * MN * NN, 256, 0, stream>>>(
        x, b3, x1g, A1g, A2g, v2g, c3g, out);
}

// Round 2
// 107.521 us; speedup vs baseline: 1.3759x; 1.3759x over previous
//
#include <hip/hip_runtime.h>

// B=4, M=8, N=128, D=32, K=2D=H=64
#define BB 4
#define MM 8
#define BM 32
#define NN 128
#define DD 32
#define KK 64
constexpr int ND = NN * DD;   // 4096
constexpr int NK = NN * KK;   // 8192
#define SMALLV 1e-8f

__device__ __forceinline__ float gelu_t(float v) {
    // 0.5*v*(1+tanh(0.79788456*(v+0.044715 v^3))), tanh(u)=1-2/(exp2(u*2.885390)+1)
    float v2 = v * v;
    float u  = v * fmaf(0.044715f, v2, 1.0f) * 0.7978845608028654f;
    float e  = __builtin_amdgcn_exp2f(u * 2.8853900817779268f);
    float r  = __builtin_amdgcn_rcpf(e + 1.0f);
    float th = fmaf(-2.0f, r, 1.0f);
    float hv = 0.5f * v;
    return fmaf(hv, th, hv);
}

// ---------------------------------------------------------------------------
// Kernel 1: per-(b,m) set-norm statistics + row mask. 32 blocks x 512.
// ---------------------------------------------------------------------------
__global__ __launch_bounds__(512) void stats_kernel(
    const float* __restrict__ x, const float* __restrict__ x_size,
    float* __restrict__ statsg, float* __restrict__ maskg)
{
    __shared__ float sAny[NN];
    __shared__ float sRed[8];
    const int t = threadIdx.x, bm = blockIdx.x;
    const float* xp = x + (size_t)bm * ND;
    float v[8];
    float lsum = 0.f;
    #pragma unroll
    for (int s = 0; s < 8; ++s) { v[s] = xp[t + s * 512]; lsum += v[s]; }
    if (t < NN) sAny[t] = 0.f;
    __syncthreads();
    #pragma unroll
    for (int s = 0; s < 8; ++s) if (v[s] != 0.f) sAny[(t + s * 512) >> 5] = 1.f;
    #pragma unroll
    for (int off = 32; off; off >>= 1) lsum += __shfl_xor(lsum, off);
    if ((t & 63) == 0) sRed[t >> 6] = lsum;
    __syncthreads();           // covers sAny flags + sRed
    float tot = 0.f;
    #pragma unroll
    for (int w = 0; w < 8; ++w) tot += sRed[w];
    const float denom = x_size[bm >> 3] * (float)DD;
    const float mean  = tot / denom;
    float lsq = 0.f;
    #pragma unroll
    for (int s = 0; s < 8; ++s) {
        float d = v[s] - mean;
        lsq += (sAny[(t + s * 512) >> 5] != 0.f) ? d * d : 0.f;
    }
    #pragma unroll
    for (int off = 32; off; off >>= 1) lsq += __shfl_xor(lsq, off);
    __syncthreads();
    if ((t & 63) == 0) sRed[t >> 6] = lsq;
    __syncthreads();
    float sq = 0.f;
    #pragma unroll
    for (int w = 0; w < 8; ++w) sq += sRed[w];
    const float inv = 1.f / (sqrtf(sq / denom) + SMALLV);
    if (t == 0) { statsg[bm * 2] = mean; statsg[bm * 2 + 1] = inv; }
    if (t < NN) maskg[bm * NN + t] = sAny[t];
}

// ---------------------------------------------------------------------------
// Kernel 2: MLP1 + A1/A2, parallel over (bm, 16-row tile). 256 blocks x 256.
// Weight COLUMNS held in registers; activations broadcast from LDS.
// ---------------------------------------------------------------------------
__global__ __launch_bounds__(256) void mlp_kernel(
    const float* __restrict__ x, const float* __restrict__ statsg,
    const float* __restrict__ maskg,
    const float* __restrict__ W1a, const float* __restrict__ b1a,
    const float* __restrict__ W1b, const float* __restrict__ b1b,
    const float* __restrict__ W2a, const float* __restrict__ b2a,
    const float* __restrict__ W2b, const float* __restrict__ b2b,
    const float* __restrict__ w3,
    float* __restrict__ x1g, float* __restrict__ A1g, float* __restrict__ A2t,
    float* __restrict__ v2g, float* __restrict__ c3g)
{
    __shared__ float sXn[16 * DD];
    __shared__ float sH[16 * KK];
    __shared__ float sX1[16 * DD];
    const int t  = threadIdx.x;
    const int bm = blockIdx.x >> 3;
    const int nt = blockIdx.x & 7;
    const int n0 = nt * 16;
    const float mean = statsg[bm * 2], inv = statsg[bm * 2 + 1];

    #pragma unroll
    for (int s = 0; s < 2; ++s) {
        int idx = t + s * 256;                 // 0..511 over 16 rows x 32
        float mk = maskg[bm * NN + n0 + (idx >> 5)];
        float xv = x[(size_t)bm * ND + n0 * DD + idx];
        sXn[idx] = (xv - mean) * inv * mk;
    }
    __syncthreads();

    // H = gelu(xn @ W1a + b1a): thread = (k, 4 rows)
    const int k   = t & 63;
    const int ns0 = t >> 6;
    {
        float wc[DD];
        #pragma unroll
        for (int d = 0; d < DD; ++d) wc[d] = W1a[d * KK + k];
        float bk = b1a[k];
        #pragma unroll
        for (int r = 0; r < 4; ++r) {
            int n = ns0 + r * 4;
            const float* xr = &sXn[n * DD];
            float acc = bk;
            #pragma unroll
            for (int d = 0; d < DD; ++d) acc = fmaf(xr[d], wc[d], acc);
            sH[n * KK + k] = gelu_t(acc);
        }
    }
    __syncthreads();

    // x1 = (H @ W1b + b1b) * mask: thread = (d, 2 rows)
    {
        const int d2  = t & 31;
        const int ns1 = t >> 5;
        float wc[KK];
        #pragma unroll
        for (int q = 0; q < KK; ++q) wc[q] = W1b[q * DD + d2];
        float bd = b1b[d2];
        #pragma unroll
        for (int r = 0; r < 2; ++r) {
            int n = ns1 + r * 8;
            const float* hr = &sH[n * KK];
            float acc = bd;
            #pragma unroll
            for (int q = 0; q < KK; ++q) acc = fmaf(hr[q], wc[q], acc);
            float val = acc * maskg[bm * NN + n0 + n];
            sX1[n * DD + d2] = val;
            x1g[(size_t)bm * ND + (n0 + n) * DD + d2] = val;
        }
    }
    __syncthreads();

    // A1 = x1@W2a + b2a ; A2 = xn@W2a (transposed store): thread = (k, 4 rows)
    {
        float wc[DD];
        #pragma unroll
        for (int d = 0; d < DD; ++d) wc[d] = W2a[d * KK + k];
        float bk = b2a[k];
        #pragma unroll
        for (int r = 0; r < 4; ++r) {
            int n = ns0 + r * 4;
            const float* x1r = &sX1[n * DD];
            const float* xnr = &sXn[n * DD];
            float a1 = bk, a2 = 0.f;
            #pragma unroll
            for (int d = 0; d < DD; ++d) {
                a1 = fmaf(x1r[d], wc[d], a1);
                a2 = fmaf(xnr[d], wc[d], a2);
            }
            A1g[(size_t)bm * NK + (n0 + n) * KK + k] = a1;
            A2t[(size_t)bm * NK + k * NN + (n0 + n)] = a2;
        }
    }

    if (blockIdx.x == 0) {
        if (t < KK) {
            float acc = 0.f;
            for (int h = 0; h < KK; ++h) acc += W2b[t * KK + h] * w3[h];
            v2g[t] = acc;
        }
        if (t == 0) {
            float acc = 0.f;
            for (int h = 0; h < KK; ++h) acc += b2b[h] * w3[h];
            c3g[0] = acc;
        }
    }
}

// ---------------------------------------------------------------------------
// Kernel 3: pair interactions. Block = (bm, j-group of 64, i-group of 16).
// lane = j; a2[64] in regs; A1/x1/v2 broadcast from LDS; acc[32] in regs.
// ---------------------------------------------------------------------------
__global__ __launch_bounds__(256) void pair_kernel(
    const float* __restrict__ A1g, const float* __restrict__ A2t,
    const float* __restrict__ x1g, const float* __restrict__ v2g,
    const float* __restrict__ c3g, float* __restrict__ partial)
{
    __shared__ float sA1[16 * KK];
    __shared__ float sX1[16 * DD];
    __shared__ float sV2[KK];
    __shared__ float sPart[4][64][DD + 1];
    const int t    = threadIdx.x;
    const int bm   = blockIdx.x >> 4;
    const int jg   = (blockIdx.x >> 3) & 1;
    const int ig   = blockIdx.x & 7;
    const int w    = t >> 6;
    const int lane = t & 63;

    #pragma unroll
    for (int s = 0; s < 4; ++s)
        sA1[t + s * 256] = A1g[(size_t)bm * NK + ig * 1024 + t + s * 256];
    #pragma unroll
    for (int s = 0; s < 2; ++s)
        sX1[t + s * 256] = x1g[(size_t)bm * ND + ig * 512 + t + s * 256];
    if (t < KK) sV2[t] = v2g[t];
    const float c3 = c3g[0];

    float a2r[KK];
    #pragma unroll
    for (int q = 0; q < KK; ++q)
        a2r[q] = A2t[(size_t)bm * NK + q * NN + jg * 64 + lane];

    float acc[DD];
    #pragma unroll
    for (int d = 0; d < DD; ++d) acc[d] = 0.f;
    __syncthreads();

    const float4* v2f = (const float4*)sV2;
    #pragma unroll
    for (int ii = 0; ii < 4; ++ii) {
        const int i = w * 4 + ii;
        const float4* a1f = (const float4*)&sA1[i * KK];
        const float4* x1f = (const float4*)&sX1[i * DD];
        float S = c3;
        #pragma unroll
        for (int kq = 0; kq < 16; ++kq) {
            float4 a  = a1f[kq];
            float4 vv = v2f[kq];
            S = fmaf(gelu_t(a.x - a2r[kq * 4 + 0]), vv.x, S);
            S = fmaf(gelu_t(a.y - a2r[kq * 4 + 1]), vv.y, S);
            S = fmaf(gelu_t(a.z - a2r[kq * 4 + 2]), vv.z, S);
            S = fmaf(gelu_t(a.w - a2r[kq * 4 + 3]), vv.w, S);
        }
        #pragma unroll
        for (int dq = 0; dq < 8; ++dq) {
            float4 xv = x1f[dq];
            acc[dq * 4 + 0] = fmaf(S, xv.x, acc[dq * 4 + 0]);
            acc[dq * 4 + 1] = fmaf(S, xv.y, acc[dq * 4 + 1]);
            acc[dq * 4 + 2] = fmaf(S, xv.z, acc[dq * 4 + 2]);
            acc[dq * 4 + 3] = fmaf(S, xv.w, acc[dq * 4 + 3]);
        }
    }
    #pragma unroll
    for (int d = 0; d < DD; ++d) sPart[w][lane][d] = acc[d];
    __syncthreads();

    const size_t base = (size_t)blockIdx.x * 2048;   // layout [bm][jg][ig][jl][d]
    #pragma unroll
    for (int s = 0; s < 8; ++s) {
        int idx = t + s * 256;
        int jl = idx >> 5, d = idx & 31;
        partial[base + idx] =
            sPart[0][jl][d] + sPart[1][jl][d] + sPart[2][jl][d] + sPart[3][jl][d];
    }
}

// ---------------------------------------------------------------------------
// Kernel 4: sum 8 i-group partials, add b3 + residual, apply item mask.
// ---------------------------------------------------------------------------
__global__ __launch_bounds__(256) void final_kernel(
    const float* __restrict__ x, const float* __restrict__ b3,
    const float* __restrict__ partial, float* __restrict__ out)
{
    const int gid = blockIdx.x * 256 + threadIdx.x;   // < 131072
    const int j = gid >> 5;
    const int bm = j >> 7, jg = (j >> 6) & 1, jl = j & 63;
    const size_t pb = ((size_t)(bm * 2 + jg) * 8) * 2048 + (jl << 5) + (gid & 31);
    float sum = 0.f;
    #pragma unroll
    for (int ig = 0; ig < 8; ++ig) sum += partial[pb + ig * 2048];
    float xv = x[gid];
    unsigned long long bal = __ballot(xv != 0.f);
    int lane = threadIdx.x & 63;
    unsigned long long half = (lane < 32) ? (bal & 0xFFFFFFFFull) : (bal >> 32);
    float mk = half ? 1.f : 0.f;
    out[gid] = (sum + b3[0] + xv) * mk;
}

extern "C" void kernel_launch(void* const* d_in, const int* in_sizes, int n_in,
                              void* d_out, int out_size, void* d_ws, size_t ws_size,
                              hipStream_t stream) {
    const float* x      = (const float*)d_in[0];
    const float* x_size = (const float*)d_in[1];
    const float* W1a    = (const float*)d_in[2];
    const float* b1a    = (const float*)d_in[3];
    const float* W1b    = (const float*)d_in[4];
    const float* b1b    = (const float*)d_in[5];
    const float* W2a    = (const float*)d_in[6];
    const float* b2a    = (const float*)d_in[7];
    const float* W2b    = (const float*)d_in[8];
    const float* b2b    = (const float*)d_in[9];
    const float* w3     = (const float*)d_in[10];
    const float* b3     = (const float*)d_in[11];
    float* out = (float*)d_out;

    float* ws      = (float*)d_ws;
    float* statsg  = ws;                      // 64
    float* maskg   = statsg + 64;             // 4096
    float* x1g     = maskg + 4096;            // 131072
    float* A1g     = x1g + (size_t)BM * ND;   // 262144
    float* A2t     = A1g + (size_t)BM * NK;   // 262144
    float* v2g     = A2t + (size_t)BM * NK;   // 64
    float* c3g     = v2g + KK;                // 1 (+63 pad)
    float* partial = c3g + 64;                // 512*2048 = 1048576

    stats_kernel<<<BM, 512, 0, stream>>>(x, x_size, statsg, maskg);
    mlp_kernel<<<BM * 8, 256, 0, stream>>>(x, statsg, maskg,
        W1a, b1a, W1b, b1b, W2a, b2a, W2b, b2b, w3,
        x1g, A1g, A2t, v2g, c3g);
    pair_kernel<<<BM * 16, 256, 0, stream>>>(A1g, A2t, x1g, v2g, c3g, partial);
    final_kernel<<<512, 256, 0, stream>>>(x, b3, partial, out);
}